// Round 2
// baseline (197.429 us; speedup 1.0000x reference)
//
#include <hip/hip_runtime.h>
#include <math.h>

// QueryEmb: B=4,L=512,D=512,V=32000, 4 segments of 8000, TEMP=sqrt(512).
// Equivalences: (1) masked softmax == softmax over token's own segment only;
// (2) |scores|<=~0.35 -> exp() safe without max-subtraction -> plain-sum
//     denoms and trivially split-K PV.
// R12: counted-vmcnt pipeline (T4). R11's __syncthreads drained vmcnt(0)
// every step (rocprof: MfmaUtil 15%, stall-bound). Now: 3 LDS buffers
// (48KB, 3 blk/CU), depth-2 prefetch; per step:
//   s_waitcnt vmcnt(4)  (tile t done; tile t+1's 4 loads stay in flight)
//   s_barrier + sched_barrier(0)
//   stage(t+2) -> buf[(t+2)%3]   (4 gll16)
//   ds_read + 32 MFMA on buf[t%3]   (setprio(1) around MFMA clusters, T5)
// vmcnt never hits 0 until the last tile. In-order vmcnt completion makes
// vmcnt(4) safe even if the compiler interleaves unrelated loads. WAR on
// buffers: stage target was last read 2 steps ago; reads are consumed by
// MFMAs (lgkmcnt) before each wave's next barrier. LDS reads forced to
// addrspace(3) so rotating pointers in k_pv stay ds_read (flat would
// corrupt the vmcnt count). fp8 everything + XCD binding kept from R10.

constexpr int Dm   = 512;
constexpr int SEG  = 8000;
constexpr int PSTR = 8064;            // P row stride (63*128), pad rows zeroed
constexpr int NTOK = 2048;
constexpr int TIL  = 128;             // slot tile
constexpr int MAXTILES = 20;          // 2048/128 + 4 pad
constexpr int MAXSLOTS = MAXTILES * TIL;   // 2560

// ws layout (bytes)
constexpr size_t WS_DENOM = 0;                                   // 2048 f32
constexpr size_t WS_META  = 8192;                                // 8 int
constexpr size_t WS_PERM  = 8448;                                // 2560 int
constexpr size_t WS_QB8   = 32768;                               // fp8 [2560][512]
constexpr size_t WS_EB8   = WS_QB8 + (size_t)MAXSLOTS * Dm;      // fp8 [32000][512]
constexpr size_t WS_OACC  = WS_EB8 + (size_t)32000 * Dm;         // bf16 [8][512][2560]
constexpr size_t WS_ET8   = WS_OACC + (size_t)8 * Dm * MAXSLOTS * 2;  // fp8 [512][32000]
constexpr size_t WS_P8    = WS_ET8 + (size_t)Dm * 32000;         // fp8 [2560][8064]
// total ~75.7 MB (< proven 104 MB)

typedef __attribute__((ext_vector_type(4))) float f32x4;
#define LDSP __attribute__((address_space(3)))
typedef LDSP unsigned char lds_u8;

static __device__ __forceinline__ ushort f2bf(float f) {
    union { float f; unsigned u; } v; v.f = f;
    unsigned r = v.u + 0x7FFF + ((v.u >> 16) & 1);   // RNE
    return (ushort)(r >> 16);
}
static __device__ __forceinline__ float bf2f(ushort u) {
    union { unsigned u; float f; } v; v.u = ((unsigned)u) << 16;
    return v.f;
}
// pack 4 floats -> 4 OCP fp8 e4m3 bytes (byte0 = a .. byte3 = d)
static __device__ __forceinline__ int pack_fp8x4(float a, float b, float c, float d) {
    int r = __builtin_amdgcn_cvt_pk_fp8_f32(a, b, 0, false);
    r = __builtin_amdgcn_cvt_pk_fp8_f32(c, d, r, true);
    return r;
}

// async global(16B/lane) -> LDS(wave-uniform base + lane*16)
static __device__ __forceinline__ void gll16(const void* g, lds_u8* l) {
    __builtin_amdgcn_global_load_lds(
        (const __attribute__((address_space(1))) unsigned int*)g,
        (LDSP unsigned int*)l, 16, 0, 0);
}

#define WAIT4 asm volatile("s_waitcnt vmcnt(4)" ::: "memory")
#define WAIT0 asm volatile("s_waitcnt vmcnt(0)" ::: "memory")
#define BARX  { __builtin_amdgcn_s_barrier(); __builtin_amdgcn_sched_barrier(0); }

// stage one BK=64 tile (16 KB/block): 4 gll16 per thread
#define STAGE4(DST, TI)                                                        \
    {                                                                          \
        _Pragma("unroll")                                                      \
        for (int i = 0; i < 4; ++i)                                            \
            gll16(pre[i] + (TI)*64, (DST) + (w*256 + i*64)*16);                \
    }

// compute one BK=64 tile from CUR (2 k-chunks of 32, 16 MFMA each)
#define CSTEP(CUR)                                                             \
    {                                                                          \
        long A[4], B[4];                                                       \
        const int cg0 = (quad >> 1), ho = (quad & 1) * 8;                      \
        _Pragma("unroll")                                                      \
        for (int m = 0; m < 4; ++m) {                                          \
            const int row = rh*64 + m*16 + l15;                                \
            A[m] = *(const LDSP long*)((CUR) + row*128 + ((cg0) ^ (row & 7))*16 + ho);\
        }                                                                      \
        _Pragma("unroll")                                                      \
        for (int n = 0; n < 4; ++n) {                                          \
            const int row = th*64 + n*16 + l15;                                \
            B[n] = *(const LDSP long*)((CUR) + row*128 + ((4 + cg0) ^ (row & 7))*16 + ho);\
        }                                                                      \
        __builtin_amdgcn_s_setprio(1);                                         \
        _Pragma("unroll")                                                      \
        for (int m = 0; m < 4; ++m)                                            \
            _Pragma("unroll")                                                  \
            for (int n = 0; n < 4; ++n)                                        \
                acc[m][n] = __builtin_amdgcn_mfma_f32_16x16x32_fp8_fp8(A[m], B[n], acc[m][n], 0, 0, 0); \
        __builtin_amdgcn_s_setprio(0);                                         \
        _Pragma("unroll")                                                      \
        for (int m = 0; m < 4; ++m) {                                          \
            const int row = rh*64 + m*16 + l15;                                \
            A[m] = *(const LDSP long*)((CUR) + row*128 + ((2 + cg0) ^ (row & 7))*16 + ho);\
        }                                                                      \
        _Pragma("unroll")                                                      \
        for (int n = 0; n < 4; ++n) {                                          \
            const int row = th*64 + n*16 + l15;                                \
            B[n] = *(const LDSP long*)((CUR) + row*128 + ((6 + cg0) ^ (row & 7))*16 + ho);\
        }                                                                      \
        __builtin_amdgcn_s_setprio(1);                                         \
        _Pragma("unroll")                                                      \
        for (int m = 0; m < 4; ++m)                                            \
            _Pragma("unroll")                                                  \
            for (int n = 0; n < 4; ++n)                                        \
                acc[m][n] = __builtin_amdgcn_mfma_f32_16x16x32_fp8_fp8(A[m], B[n], acc[m][n], 0, 0, 0); \
        __builtin_amdgcn_s_setprio(0);                                         \
    }

// ---- K1: sort tokens by rank into 128-padded slot regions (1 block) ----
__global__ __launch_bounds__(256)
void k_prep(const int* __restrict__ xr, int* __restrict__ meta, int* __restrict__ perm,
            float* __restrict__ denom) {
    __shared__ int cnt[4], base[5], cur[4];
    const int tid = threadIdx.x;
    if (tid < 4) { cnt[tid] = 0; cur[tid] = 0; }
    __syncthreads();
    for (int t = tid; t < NTOK; t += 256) {
        atomicAdd(&cnt[xr[t]], 1);
        denom[t] = 0.f;
    }
    __syncthreads();
    if (tid == 0) {
        base[0] = 0;
        for (int r = 0; r < 4; ++r) base[r+1] = base[r] + ((cnt[r] + TIL - 1) / TIL) * TIL;
        for (int r = 0; r < 5; ++r) meta[r] = base[r];
    }
    __syncthreads();
    for (int s = tid; s < MAXSLOTS; s += 256) perm[s] = -1;
    __syncthreads();
    for (int t = tid; t < NTOK; t += 256) {
        int r = xr[t];
        perm[base[r] + atomicAdd(&cur[r], 1)] = t;
    }
}

// ---- K2: emb fp32 -> EB8 fp8 row-major + ET8 fp8 transposed ----
__global__ __launch_bounds__(256)
void k_conv(const float* __restrict__ emb, unsigned char* __restrict__ EB8,
            unsigned char* __restrict__ ET8) {
    __shared__ unsigned char sT[64 * 8 * 16];   // 8 KB
    const int tid = threadIdx.x;
    const int r0 = blockIdx.x * 128, d0 = blockIdx.y * 64;
    {
        const int dq = tid & 15, ro = tid >> 4;     // 4-d group, 8-row group
        int p[8];
        #pragma unroll
        for (int i = 0; i < 8; ++i) {
            float4 v = *(const float4*)(emb + (size_t)(r0 + ro*8 + i) * Dm + d0 + dq*4);
            p[i] = pack_fp8x4(v.x, v.y, v.z, v.w);
            *(int*)(EB8 + (size_t)(r0 + ro*8 + i) * Dm + d0 + dq*4) = p[i];
        }
        const int gr = ro >> 1, half = ro & 1;
        #pragma unroll
        for (int j = 0; j < 4; ++j) {               // per d: pack 8 row-bytes
            const int d = dq*4 + j;
            unsigned long long t = 0;
            #pragma unroll
            for (int i = 0; i < 8; ++i)
                t |= ((unsigned long long)((p[i] >> (8*j)) & 0xff)) << (8*i);
            *(unsigned long long*)(sT + (d*8 + (gr ^ (d & 7))) * 16 + half * 8) = t;
        }
    }
    __syncthreads();
    {
        const int d = tid >> 2, rq = tid & 3;
        unsigned char* dst = ET8 + (size_t)(d0 + d) * 32000 + r0;
        #pragma unroll
        for (int b = 0; b < 2; ++b) {
            const int gr = rq * 2 + b;
            *(uint4*)(dst + gr * 16) = *(const uint4*)(sT + (d*8 + (gr ^ (d & 7))) * 16);
        }
    }
}

// ---- K2b: gather Q -> Qb8 fp8 [2560 slots][512] (pad slots zeroed) ----
__global__ __launch_bounds__(256)
void k_qb(const float* __restrict__ q, const int* __restrict__ perm,
          unsigned char* __restrict__ Qb8) {
    const int slot = blockIdx.x * 8 + (threadIdx.x >> 5);
    const int ln = threadIdx.x & 31;
    const int tok = perm[slot];
    #pragma unroll
    for (int j = 0; j < 4; ++j) {
        const int c4 = ln + j * 32;
        int p = 0;
        if (tok >= 0) {
            float4 v = ((const float4*)q)[(size_t)tok * 128 + c4];
            p = pack_fp8x4(v.x, v.y, v.z, v.w);
        }
        ((int*)(Qb8 + (size_t)slot * Dm))[c4] = p;
    }
}

// ---- K3: S^T = E.Q^T fp8, counted-vmcnt pipeline; exp -> P8 + denoms ----
__global__ __launch_bounds__(256, 3)
void k_qk(const unsigned char* __restrict__ EB8, const unsigned char* __restrict__ Qb8,
          const int* __restrict__ meta, const int* __restrict__ perm,
          float* __restrict__ denom, unsigned char* __restrict__ P8) {
    __shared__ unsigned char s0[128 * 128];   // 16 KB unified A|B tile (BK=64)
    __shared__ unsigned char s1[128 * 128];
    __shared__ unsigned char s2[128 * 128];
    const int tid = threadIdx.x, lane = tid & 63, w = tid >> 6;
    const int g    = blockIdx.x & 7;              // XCD group
    const int rest = blockIdx.x >> 3;
    const int rt_local = rest / MAXTILES;         // 0..7
    const int tt       = rest % MAXTILES;
    const int c = g * 8 + rt_local;               // row-tile 0..63
    const int slot0 = tt * TIL;
    const int b1 = meta[1], b2 = meta[2], b3 = meta[3], b4 = meta[4];
    if (slot0 >= b4) return;
    const int row0 = c * 128;
    if (row0 >= PSTR) return;                     // c==63: provably writes nothing
    const int rank = (slot0 >= b1) + (slot0 >= b2) + (slot0 >= b3);

    // per-thread source pointers for the 4 staged granules (16 B each).
    // granule gg: LDS row r = gg>>3, unit u = gg&7; content cg = u ^ (r&7):
    // cg<4 -> A (EB8 row, k-granule cg), cg>=4 -> B (Qb8 slot row, cg-4)
    const unsigned char* pre[4];
    #pragma unroll
    for (int i = 0; i < 4; ++i) {
        const int gg = w * 256 + i * 64 + lane;
        const int r = gg >> 3, u = gg & 7, cg = u ^ (r & 7);
        if (cg < 4) {
            int grow = row0 + r;
            if (grow >= SEG) grow = SEG - 1;      // clamp; outputs masked
            pre[i] = EB8 + (size_t)rank * SEG * Dm + (size_t)grow * Dm + cg * 16;
        } else {
            pre[i] = Qb8 + (size_t)(slot0 + r) * Dm + (cg - 4) * 16;
        }
    }
    const int rh = w >> 1, th = w & 1, quad = lane >> 4, l15 = lane & 15;
    const float invT = 0.04419417382415922f;   // 1/sqrt(512)
    lds_u8* b0p = (lds_u8*)s0;
    lds_u8* b1p = (lds_u8*)s1;
    lds_u8* b2p = (lds_u8*)s2;

    f32x4 acc[4][4] = {};
    STAGE4(b0p, 0)                                // prologue: tiles 0,1 in flight
    STAGE4(b1p, 1)
    WAIT4; BARX; STAGE4(b2p, 2) CSTEP(b0p)        // t=0
    WAIT4; BARX; STAGE4(b0p, 3) CSTEP(b1p)        // t=1
    WAIT4; BARX; STAGE4(b1p, 4) CSTEP(b2p)        // t=2
    WAIT4; BARX; STAGE4(b2p, 5) CSTEP(b0p)        // t=3
    WAIT4; BARX; STAGE4(b0p, 6) CSTEP(b1p)        // t=4
    WAIT4; BARX; STAGE4(b1p, 7) CSTEP(b2p)        // t=5
    WAIT4; BARX; CSTEP(b0p)                       // t=6
    WAIT0; BARX; CSTEP(b1p)                       // t=7

    float dsum[4] = {0.f, 0.f, 0.f, 0.f};
    #pragma unroll
    for (int m = 0; m < 4; ++m) {
        const int r4 = row0 + rh*64 + m*16 + quad*4;
        if (r4 < SEG) {
            #pragma unroll
            for (int n = 0; n < 4; ++n) {
                float e0 = __expf(acc[m][n][0] * invT);
                float e1 = __expf(acc[m][n][1] * invT);
                float e2 = __expf(acc[m][n][2] * invT);
                float e3 = __expf(acc[m][n][3] * invT);
                const int slot = slot0 + th*64 + n*16 + l15;
                *(int*)(P8 + (size_t)slot * PSTR + r4) = pack_fp8x4(e0, e1, e2, e3);
                dsum[n] += e0 + e1 + e2 + e3;
            }
        } else if (r4 < PSTR) {                // zero the pad rows (k_pv tail)
            #pragma unroll
            for (int n = 0; n < 4; ++n) {
                const int slot = slot0 + th*64 + n*16 + l15;
                *(int*)(P8 + (size_t)slot * PSTR + r4) = 0;
            }
        }
    }
    #pragma unroll
    for (int n = 0; n < 4; ++n) {
        float s = dsum[n];
        s += __shfl_xor(s, 16, 64);
        s += __shfl_xor(s, 32, 64);
        if (quad == 0) {
            const int tok = perm[slot0 + th*64 + n*16 + l15];
            if (tok >= 0) atomicAdd(denom + tok, s);
        }
    }
}

// ---- K4: O^T = E^T.P^T fp8, counted-vmcnt pipeline; K-split z = XCD ----
__global__ __launch_bounds__(256, 3)
void k_pv(const unsigned char* __restrict__ ET8, const unsigned char* __restrict__ P8,
          const int* __restrict__ meta, ushort* __restrict__ Oacc) {
    __shared__ unsigned char s0[128 * 128];
    __shared__ unsigned char s1[128 * 128];
    __shared__ unsigned char s2[128 * 128];
    const int tid = threadIdx.x, lane = tid & 63, w = tid >> 6;
    const int z    = blockIdx.x & 7;              // K-split == XCD group
    const int rest = blockIdx.x >> 3;
    const int dt   = rest / MAXTILES;             // d-tile 0..3
    const int tt   = rest % MAXTILES;
    const int slot0 = tt * TIL;
    const int b1 = meta[1], b2 = meta[2], b3 = meta[3], b4 = meta[4];
    if (slot0 >= b4) return;
    const int rank = (slot0 >= b1) + (slot0 >= b2) + (slot0 >= b3);
    const int d0 = dt * 128;
    const int kstart = z * 1024;
    const int nit = (z == 7) ? 14 : 16;           // BK=64: 7*16+14 = 126 -> 8064 rows

    const unsigned char* pre[4];
    #pragma unroll
    for (int i = 0; i < 4; ++i) {
        const int gg = w * 256 + i * 64 + lane;
        const int r = gg >> 3, u = gg & 7, cg = u ^ (r & 7);
        if (cg < 4)   // v>=8000 reads x P8-pad 0
            pre[i] = ET8 + (size_t)(d0 + r) * 32000 + (size_t)rank * SEG + kstart + cg * 16;
        else
            pre[i] = P8 + (size_t)(slot0 + r) * PSTR + kstart + (cg - 4) * 16;
    }
    const int rh = w >> 1, th = w & 1, quad = lane >> 4, l15 = lane & 15;

    f32x4 acc[4][4] = {};
    lds_u8* cu = (lds_u8*)s0;
    lds_u8* n1 = (lds_u8*)s1;
    lds_u8* n2 = (lds_u8*)s2;
    STAGE4(cu, 0)                                 // prologue: tiles 0,1 in flight
    STAGE4(n1, 1)
    for (int t = 0; t < nit - 1; ++t) {
        WAIT4; BARX;
        if (t + 2 < nit) STAGE4(n2, t + 2)
        CSTEP(cu)
        lds_u8* tp = cu; cu = n1; n1 = n2; n2 = tp;
    }
    WAIT0; BARX; CSTEP(cu)

    ushort* Oz = Oacc + (size_t)z * Dm * MAXSLOTS;
    #pragma unroll
    for (int m = 0; m < 4; ++m) {
        const int d4 = d0 + rh*64 + m*16 + quad*4;
        #pragma unroll
        for (int n = 0; n < 4; ++n) {
            const int slot = slot0 + th*64 + n*16 + l15;
            #pragma unroll
            for (int j = 0; j < 4; ++j)
                Oz[(size_t)(d4 + j) * MAXSLOTS + slot] = f2bf(acc[m][n][j]);
        }
    }
}

// ---- K5: out[tok][d] = (sum_z Oacc[z][d][slot]) / denom + q ----
__global__ __launch_bounds__(256)
void k_final(const float* __restrict__ q, const int* __restrict__ meta,
             const int* __restrict__ perm, const float* __restrict__ denom,
             const ushort* __restrict__ Oacc, float* __restrict__ out) {
    const int d = blockIdx.x;
    const int ns = meta[4];
    for (int s = threadIdx.x; s < ns; s += 256) {
        const int tok = perm[s];
        if (tok < 0) continue;
        float v = 0.f;
        #pragma unroll
        for (int z = 0; z < 8; ++z)
            v += bf2f(Oacc[((size_t)z * Dm + d) * MAXSLOTS + s]);
        out[(size_t)tok * Dm + d] = v / denom[tok] + q[(size_t)tok * Dm + d];
    }
}

extern "C" void kernel_launch(void* const* d_in, const int* in_sizes, int n_in,
                              void* d_out, int out_size, void* d_ws, size_t ws_size,
                              hipStream_t stream) {
    const float* q   = (const float*)d_in[0];
    const int*   xr  = (const int*)d_in[1];
    const float* emb = (const float*)d_in[2];
    float* out = (float*)d_out;
    char* ws = (char*)d_ws;

    float*  denom        = (float*)(ws + WS_DENOM);
    int*    meta         = (int*)(ws + WS_META);
    int*    perm         = (int*)(ws + WS_PERM);
    unsigned char* Qb8   = (unsigned char*)(ws + WS_QB8);
    unsigned char* EB8   = (unsigned char*)(ws + WS_EB8);
    ushort* Oacc         = (ushort*)(ws + WS_OACC);
    unsigned char* ET8   = (unsigned char*)(ws + WS_ET8);
    unsigned char* P8    = (unsigned char*)(ws + WS_P8);

    k_prep<<<1, 256, 0, stream>>>(xr, meta, perm, denom);
    k_conv<<<dim3(250, 8), 256, 0, stream>>>(emb, EB8, ET8);
    k_qb<<<MAXSLOTS / 8, 256, 0, stream>>>(q, perm, Qb8);
    k_qk<<<8 * 8 * MAXTILES, 256, 0, stream>>>(EB8, Qb8, meta, perm, denom, P8);
    k_pv<<<8 * 4 * MAXTILES, 256, 0, stream>>>(ET8, P8, meta, Oacc);
    k_final<<<Dm, 256, 0, stream>>>(q, meta, perm, denom, Oacc, out);
}

// Round 4
// 191.003 us; speedup vs baseline: 1.0336x; 1.0336x over previous
//
#include <hip/hip_runtime.h>
#include <math.h>

// QueryEmb: B=4,L=512,D=512,V=32000, 4 segments of 8000, TEMP=sqrt(512).
// Equivalences: (1) masked softmax == softmax over token's own segment only;
// (2) |scores|<=~0.35 -> exp() safe without max-subtraction -> plain-sum
//     denoms and trivially split-K PV.
// R14 = R13 with the addrspace(3) compile fix (u32x4 ext_vector instead of
// HIP's class-type uint4). Reg-staged pipeline (T14): R10/R11/R12
// (gll-staging under 3 different schedules) all pinned at 41 us for k_qk:
// with global_load_lds outstanding, the backend drains vmcnt(0) at every
// s_barrier, so all schedules collapse to the same stall. Now:
// global->VGPR (4x dwordx4, issued BEFORE the step's MFMAs) -> vmcnt(0)
// (a full compute phase of slack) -> ds_write_b128 -> lgkmcnt(0) ->
// s_barrier. 2 buffers, 32KB LDS, launch_bounds(256,4). tt-outer grid
// order (tail blocks dispatch last), k_prep folded into k_conv.

constexpr int Dm   = 512;
constexpr int SEG  = 8000;
constexpr int PSTR = 8064;            // P row stride (63*128), pad rows zeroed
constexpr int NTOK = 2048;
constexpr int TIL  = 128;             // slot tile
constexpr int MAXTILES = 20;          // 2048/128 + 4 pad
constexpr int MAXSLOTS = MAXTILES * TIL;   // 2560

// ws layout (bytes)
constexpr size_t WS_DENOM = 0;                                   // 2048 f32
constexpr size_t WS_META  = 8192;                                // 8 int
constexpr size_t WS_PERM  = 8448;                                // 2560 int
constexpr size_t WS_QB8   = 32768;                               // fp8 [2560][512]
constexpr size_t WS_EB8   = WS_QB8 + (size_t)MAXSLOTS * Dm;      // fp8 [32000][512]
constexpr size_t WS_OACC  = WS_EB8 + (size_t)32000 * Dm;         // bf16 [8][512][2560]
constexpr size_t WS_ET8   = WS_OACC + (size_t)8 * Dm * MAXSLOTS * 2;  // fp8 [512][32000]
constexpr size_t WS_P8    = WS_ET8 + (size_t)Dm * 32000;         // fp8 [2560][8064]
// total ~75.7 MB (< proven 104 MB)

typedef __attribute__((ext_vector_type(4))) float f32x4;
typedef __attribute__((ext_vector_type(4))) unsigned int u32x4;
#define LDSP __attribute__((address_space(3)))
typedef LDSP unsigned char lds_u8;
typedef LDSP u32x4 lds_v4;

static __device__ __forceinline__ ushort f2bf(float f) {
    union { float f; unsigned u; } v; v.f = f;
    unsigned r = v.u + 0x7FFF + ((v.u >> 16) & 1);   // RNE
    return (ushort)(r >> 16);
}
static __device__ __forceinline__ float bf2f(ushort u) {
    union { unsigned u; float f; } v; v.u = ((unsigned)u) << 16;
    return v.f;
}
// pack 4 floats -> 4 OCP fp8 e4m3 bytes (byte0 = a .. byte3 = d)
static __device__ __forceinline__ int pack_fp8x4(float a, float b, float c, float d) {
    int r = __builtin_amdgcn_cvt_pk_fp8_f32(a, b, 0, false);
    r = __builtin_amdgcn_cvt_pk_fp8_f32(c, d, r, true);
    return r;
}

#define WAIT0 asm volatile("s_waitcnt vmcnt(0)" ::: "memory")
#define LGKM0 asm volatile("s_waitcnt lgkmcnt(0)" ::: "memory")
#define BARX  { __builtin_amdgcn_s_barrier(); __builtin_amdgcn_sched_barrier(0); }

// compute one BK=64 tile from CUR (2 k-chunks of 32, 16 MFMA each)
#define CSTEP(CUR)                                                             \
    {                                                                          \
        long A[4], B[4];                                                       \
        const int cg0 = (quad >> 1), ho = (quad & 1) * 8;                      \
        _Pragma("unroll")                                                      \
        for (int m = 0; m < 4; ++m) {                                          \
            const int row = rh*64 + m*16 + l15;                                \
            A[m] = *(const LDSP long*)((CUR) + row*128 + ((cg0) ^ (row & 7))*16 + ho);\
        }                                                                      \
        _Pragma("unroll")                                                      \
        for (int n = 0; n < 4; ++n) {                                          \
            const int row = th*64 + n*16 + l15;                                \
            B[n] = *(const LDSP long*)((CUR) + row*128 + ((4 + cg0) ^ (row & 7))*16 + ho);\
        }                                                                      \
        __builtin_amdgcn_s_setprio(1);                                         \
        _Pragma("unroll")                                                      \
        for (int m = 0; m < 4; ++m)                                            \
            _Pragma("unroll")                                                  \
            for (int n = 0; n < 4; ++n)                                        \
                acc[m][n] = __builtin_amdgcn_mfma_f32_16x16x32_fp8_fp8(A[m], B[n], acc[m][n], 0, 0, 0); \
        __builtin_amdgcn_s_setprio(0);                                         \
        _Pragma("unroll")                                                      \
        for (int m = 0; m < 4; ++m) {                                          \
            const int row = rh*64 + m*16 + l15;                                \
            A[m] = *(const LDSP long*)((CUR) + row*128 + ((2 + cg0) ^ (row & 7))*16 + ho);\
        }                                                                      \
        _Pragma("unroll")                                                      \
        for (int n = 0; n < 4; ++n) {                                          \
            const int row = th*64 + n*16 + l15;                                \
            B[n] = *(const LDSP long*)((CUR) + row*128 + ((6 + cg0) ^ (row & 7))*16 + ho);\
        }                                                                      \
        __builtin_amdgcn_s_setprio(1);                                         \
        _Pragma("unroll")                                                      \
        for (int m = 0; m < 4; ++m)                                            \
            _Pragma("unroll")                                                  \
            for (int n = 0; n < 4; ++n)                                        \
                acc[m][n] = __builtin_amdgcn_mfma_f32_16x16x32_fp8_fp8(A[m], B[n], acc[m][n], 0, 0, 0); \
        __builtin_amdgcn_s_setprio(0);                                         \
    }

// reg-staged pipeline step: issue loads for tile TIN early, compute CUR,
// then wait/ds_write TIN into NXT and barrier.
#define PSTEP(CUR, NXT, TIN)                                                   \
    {                                                                          \
        u32x4 st0 = *(const u32x4*)(pre[0] + (TIN)*64);                        \
        u32x4 st1 = *(const u32x4*)(pre[1] + (TIN)*64);                        \
        u32x4 st2 = *(const u32x4*)(pre[2] + (TIN)*64);                        \
        u32x4 st3 = *(const u32x4*)(pre[3] + (TIN)*64);                        \
        CSTEP(CUR)                                                             \
        WAIT0;                                                                 \
        *(lds_v4*)((NXT) + (w*256 +   0 + lane)*16) = st0;                     \
        *(lds_v4*)((NXT) + (w*256 +  64 + lane)*16) = st1;                     \
        *(lds_v4*)((NXT) + (w*256 + 128 + lane)*16) = st2;                     \
        *(lds_v4*)((NXT) + (w*256 + 192 + lane)*16) = st3;                     \
        LGKM0; BARX;                                                           \
    }

#define PROLOG(DST, TI0)                                                       \
    {                                                                          \
        u32x4 st0 = *(const u32x4*)(pre[0] + (TI0)*64);                        \
        u32x4 st1 = *(const u32x4*)(pre[1] + (TI0)*64);                        \
        u32x4 st2 = *(const u32x4*)(pre[2] + (TI0)*64);                        \
        u32x4 st3 = *(const u32x4*)(pre[3] + (TI0)*64);                        \
        WAIT0;                                                                 \
        *(lds_v4*)((DST) + (w*256 +   0 + lane)*16) = st0;                     \
        *(lds_v4*)((DST) + (w*256 +  64 + lane)*16) = st1;                     \
        *(lds_v4*)((DST) + (w*256 + 128 + lane)*16) = st2;                     \
        *(lds_v4*)((DST) + (w*256 + 192 + lane)*16) = st3;                     \
        LGKM0; BARX;                                                           \
    }

// ---- K2(+K1): emb fp32 -> EB8 fp8 + ET8 fp8 transposed; last x-block: prep ----
__global__ __launch_bounds__(256)
void k_conv(const float* __restrict__ emb, unsigned char* __restrict__ EB8,
            unsigned char* __restrict__ ET8,
            const int* __restrict__ xr, int* __restrict__ meta,
            int* __restrict__ perm, float* __restrict__ denom) {
    __shared__ unsigned char sT[64 * 8 * 16];   // 8 KB
    const int tid = threadIdx.x;
    if (blockIdx.x == 250) {                    // fused k_prep (1 block)
        if (blockIdx.y != 0) return;
        __shared__ int cnt[4], base[5], cur[4];
        if (tid < 4) { cnt[tid] = 0; cur[tid] = 0; }
        __syncthreads();
        for (int t = tid; t < NTOK; t += 256) {
            atomicAdd(&cnt[xr[t]], 1);
            denom[t] = 0.f;
        }
        __syncthreads();
        if (tid == 0) {
            base[0] = 0;
            for (int r = 0; r < 4; ++r) base[r+1] = base[r] + ((cnt[r] + TIL - 1) / TIL) * TIL;
            for (int r = 0; r < 5; ++r) meta[r] = base[r];
        }
        __syncthreads();
        for (int s = tid; s < MAXSLOTS; s += 256) perm[s] = -1;
        __syncthreads();
        for (int t = tid; t < NTOK; t += 256) {
            int r = xr[t];
            perm[base[r] + atomicAdd(&cur[r], 1)] = t;
        }
        return;
    }
    const int r0 = blockIdx.x * 128, d0 = blockIdx.y * 64;
    {
        const int dq = tid & 15, ro = tid >> 4;     // 4-d group, 8-row group
        int p[8];
        #pragma unroll
        for (int i = 0; i < 8; ++i) {
            float4 v = *(const float4*)(emb + (size_t)(r0 + ro*8 + i) * Dm + d0 + dq*4);
            p[i] = pack_fp8x4(v.x, v.y, v.z, v.w);
            *(int*)(EB8 + (size_t)(r0 + ro*8 + i) * Dm + d0 + dq*4) = p[i];
        }
        const int gr = ro >> 1, half = ro & 1;
        #pragma unroll
        for (int j = 0; j < 4; ++j) {               // per d: pack 8 row-bytes
            const int d = dq*4 + j;
            unsigned long long t = 0;
            #pragma unroll
            for (int i = 0; i < 8; ++i)
                t |= ((unsigned long long)((p[i] >> (8*j)) & 0xff)) << (8*i);
            *(unsigned long long*)(sT + (d*8 + (gr ^ (d & 7))) * 16 + half * 8) = t;
        }
    }
    __syncthreads();
    {
        const int d = tid >> 2, rq = tid & 3;
        unsigned char* dst = ET8 + (size_t)(d0 + d) * 32000 + r0;
        #pragma unroll
        for (int b = 0; b < 2; ++b) {
            const int gr = rq * 2 + b;
            *(uint4*)(dst + gr * 16) = *(const uint4*)(sT + (d*8 + (gr ^ (d & 7))) * 16);
        }
    }
}

// ---- K2b: gather Q -> Qb8 fp8 [2560 slots][512] (pad slots zeroed) ----
__global__ __launch_bounds__(256)
void k_qb(const float* __restrict__ q, const int* __restrict__ perm,
          unsigned char* __restrict__ Qb8) {
    const int slot = blockIdx.x * 8 + (threadIdx.x >> 5);
    const int ln = threadIdx.x & 31;
    const int tok = perm[slot];
    #pragma unroll
    for (int j = 0; j < 4; ++j) {
        const int c4 = ln + j * 32;
        int p = 0;
        if (tok >= 0) {
            float4 v = ((const float4*)q)[(size_t)tok * 128 + c4];
            p = pack_fp8x4(v.x, v.y, v.z, v.w);
        }
        ((int*)(Qb8 + (size_t)slot * Dm))[c4] = p;
    }
}

// ---- K3: S^T = E.Q^T fp8, reg-staged pipeline; exp -> P8 + denoms ----
__global__ __launch_bounds__(256, 4)
void k_qk(const unsigned char* __restrict__ EB8, const unsigned char* __restrict__ Qb8,
          const int* __restrict__ meta, const int* __restrict__ perm,
          float* __restrict__ denom, unsigned char* __restrict__ P8) {
    __shared__ unsigned char s0[128 * 128];   // 16 KB unified A|B tile (BK=64)
    __shared__ unsigned char s1[128 * 128];
    const int tid = threadIdx.x, lane = tid & 63, w = tid >> 6;
    const int g    = blockIdx.x & 7;              // XCD group
    const int rest = blockIdx.x >> 3;
    const int tt       = rest >> 3;               // tt-outer: tail blocks last
    const int rt_local = rest & 7;                // 0..7
    const int c = g * 8 + rt_local;               // row-tile 0..63
    const int slot0 = tt * TIL;
    const int b1 = meta[1], b2 = meta[2], b3 = meta[3], b4 = meta[4];
    if (slot0 >= b4) return;
    const int row0 = c * 128;
    if (row0 >= PSTR) return;                     // c==63: provably writes nothing
    const int rank = (slot0 >= b1) + (slot0 >= b2) + (slot0 >= b3);

    // per-thread source pointers for the 4 staged granules (16 B each).
    // granule gg: LDS row r = gg>>3, unit u = gg&7; content cg = u ^ (r&7):
    // cg<4 -> A (EB8 row, k-granule cg), cg>=4 -> B (Qb8 slot row, cg-4)
    const unsigned char* pre[4];
    #pragma unroll
    for (int i = 0; i < 4; ++i) {
        const int gg = w * 256 + i * 64 + lane;
        const int r = gg >> 3, u = gg & 7, cg = u ^ (r & 7);
        if (cg < 4) {
            int grow = row0 + r;
            if (grow >= SEG) grow = SEG - 1;      // clamp; outputs masked
            pre[i] = EB8 + (size_t)rank * SEG * Dm + (size_t)grow * Dm + cg * 16;
        } else {
            pre[i] = Qb8 + (size_t)(slot0 + r) * Dm + (cg - 4) * 16;
        }
    }
    const int rh = w >> 1, th = w & 1, quad = lane >> 4, l15 = lane & 15;
    const float invT = 0.04419417382415922f;   // 1/sqrt(512)
    lds_u8* b0p = (lds_u8*)s0;
    lds_u8* b1p = (lds_u8*)s1;

    f32x4 acc[4][4] = {};
    PROLOG(b0p, 0)
    PSTEP(b0p, b1p, 1)
    PSTEP(b1p, b0p, 2)
    PSTEP(b0p, b1p, 3)
    PSTEP(b1p, b0p, 4)
    PSTEP(b0p, b1p, 5)
    PSTEP(b1p, b0p, 6)
    PSTEP(b0p, b1p, 7)
    CSTEP(b1p)

    float dsum[4] = {0.f, 0.f, 0.f, 0.f};
    #pragma unroll
    for (int m = 0; m < 4; ++m) {
        const int r4 = row0 + rh*64 + m*16 + quad*4;
        if (r4 < SEG) {
            #pragma unroll
            for (int n = 0; n < 4; ++n) {
                float e0 = __expf(acc[m][n][0] * invT);
                float e1 = __expf(acc[m][n][1] * invT);
                float e2 = __expf(acc[m][n][2] * invT);
                float e3 = __expf(acc[m][n][3] * invT);
                const int slot = slot0 + th*64 + n*16 + l15;
                *(int*)(P8 + (size_t)slot * PSTR + r4) = pack_fp8x4(e0, e1, e2, e3);
                dsum[n] += e0 + e1 + e2 + e3;
            }
        } else if (r4 < PSTR) {                // zero the pad rows (k_pv tail)
            #pragma unroll
            for (int n = 0; n < 4; ++n) {
                const int slot = slot0 + th*64 + n*16 + l15;
                *(int*)(P8 + (size_t)slot * PSTR + r4) = 0;
            }
        }
    }
    #pragma unroll
    for (int n = 0; n < 4; ++n) {
        float s = dsum[n];
        s += __shfl_xor(s, 16, 64);
        s += __shfl_xor(s, 32, 64);
        if (quad == 0) {
            const int tok = perm[slot0 + th*64 + n*16 + l15];
            if (tok >= 0) atomicAdd(denom + tok, s);
        }
    }
}

// ---- K4: O^T = E^T.P^T fp8, reg-staged pipeline; K-split z = XCD ----
__global__ __launch_bounds__(256, 4)
void k_pv(const unsigned char* __restrict__ ET8, const unsigned char* __restrict__ P8,
          const int* __restrict__ meta, ushort* __restrict__ Oacc) {
    __shared__ unsigned char s0[128 * 128];
    __shared__ unsigned char s1[128 * 128];
    const int tid = threadIdx.x, lane = tid & 63, w = tid >> 6;
    const int z    = blockIdx.x & 7;              // K-split == XCD group
    const int rest = blockIdx.x >> 3;
    const int tt   = rest >> 2;                   // tt-outer: tail blocks last
    const int dt   = rest & 3;                    // d-tile 0..3
    const int slot0 = tt * TIL;
    const int b1 = meta[1], b2 = meta[2], b3 = meta[3], b4 = meta[4];
    if (slot0 >= b4) return;
    const int rank = (slot0 >= b1) + (slot0 >= b2) + (slot0 >= b3);
    const int d0 = dt * 128;
    const int kstart = z * 1024;
    const int nit = (z == 7) ? 14 : 16;           // BK=64: 7*16+14 = 126 -> 8064 rows

    const unsigned char* pre[4];
    #pragma unroll
    for (int i = 0; i < 4; ++i) {
        const int gg = w * 256 + i * 64 + lane;
        const int r = gg >> 3, u = gg & 7, cg = u ^ (r & 7);
        if (cg < 4)   // v>=8000 reads x P8-pad 0
            pre[i] = ET8 + (size_t)(d0 + r) * 32000 + (size_t)rank * SEG + kstart + cg * 16;
        else
            pre[i] = P8 + (size_t)(slot0 + r) * PSTR + kstart + (cg - 4) * 16;
    }
    const int rh = w >> 1, th = w & 1, quad = lane >> 4, l15 = lane & 15;
    lds_u8* b0p = (lds_u8*)s0;
    lds_u8* b1p = (lds_u8*)s1;

    f32x4 acc[4][4] = {};
    PROLOG(b0p, 0)
    for (int t2 = 0; t2 < nit/2 - 1; ++t2) {      // nit always even (16 or 14)
        PSTEP(b0p, b1p, 2*t2 + 1)
        PSTEP(b1p, b0p, 2*t2 + 2)
    }
    PSTEP(b0p, b1p, nit - 1)
    CSTEP(b1p)

    ushort* Oz = Oacc + (size_t)z * Dm * MAXSLOTS;
    #pragma unroll
    for (int m = 0; m < 4; ++m) {
        const int d4 = d0 + rh*64 + m*16 + quad*4;
        #pragma unroll
        for (int n = 0; n < 4; ++n) {
            const int slot = slot0 + th*64 + n*16 + l15;
            #pragma unroll
            for (int j = 0; j < 4; ++j)
                Oz[(size_t)(d4 + j) * MAXSLOTS + slot] = f2bf(acc[m][n][j]);
        }
    }
}

// ---- K5: out[tok][d] = (sum_z Oacc[z][d][slot]) / denom + q ----
__global__ __launch_bounds__(256)
void k_final(const float* __restrict__ q, const int* __restrict__ meta,
             const int* __restrict__ perm, const float* __restrict__ denom,
             const ushort* __restrict__ Oacc, float* __restrict__ out) {
    const int d = blockIdx.x;
    const int ns = meta[4];
    for (int s = threadIdx.x; s < ns; s += 256) {
        const int tok = perm[s];
        if (tok < 0) continue;
        float v = 0.f;
        #pragma unroll
        for (int z = 0; z < 8; ++z)
            v += bf2f(Oacc[((size_t)z * Dm + d) * MAXSLOTS + s]);
        out[(size_t)tok * Dm + d] = v / denom[tok] + q[(size_t)tok * Dm + d];
    }
}

extern "C" void kernel_launch(void* const* d_in, const int* in_sizes, int n_in,
                              void* d_out, int out_size, void* d_ws, size_t ws_size,
                              hipStream_t stream) {
    const float* q   = (const float*)d_in[0];
    const int*   xr  = (const int*)d_in[1];
    const float* emb = (const float*)d_in[2];
    float* out = (float*)d_out;
    char* ws = (char*)d_ws;

    float*  denom        = (float*)(ws + WS_DENOM);
    int*    meta         = (int*)(ws + WS_META);
    int*    perm         = (int*)(ws + WS_PERM);
    unsigned char* Qb8   = (unsigned char*)(ws + WS_QB8);
    unsigned char* EB8   = (unsigned char*)(ws + WS_EB8);
    ushort* Oacc         = (ushort*)(ws + WS_OACC);
    unsigned char* ET8   = (unsigned char*)(ws + WS_ET8);
    unsigned char* P8    = (unsigned char*)(ws + WS_P8);

    k_conv<<<dim3(251, 8), 256, 0, stream>>>(emb, EB8, ET8, xr, meta, perm, denom);
    k_qb<<<MAXSLOTS / 8, 256, 0, stream>>>(q, perm, Qb8);
    k_qk<<<8 * 8 * MAXTILES, 256, 0, stream>>>(EB8, Qb8, meta, perm, denom, P8);
    k_pv<<<8 * 4 * MAXTILES, 256, 0, stream>>>(ET8, P8, meta, Oacc);
    k_final<<<Dm, 256, 0, stream>>>(q, meta, perm, denom, Oacc, out);
}